// Round 6
// baseline (10550.438 us; speedup 1.0000x reference)
//
#include <hip/hip_runtime.h>
#include <hip/hip_bf16.h>

#define H 2048
#define T 2048
#define INPUT 1024
#define FOURH 8192
#define NBLK 256
#define RING 512  // ring slots; epoch barrier every 256 steps bounds skew < 512

typedef __attribute__((ext_vector_type(8))) short bf16x8;
typedef __attribute__((ext_vector_type(4))) float f32x4_t;

__device__ __forceinline__ unsigned short f2bf(float f) {
  union { float f; unsigned u; } v; v.f = f;
  unsigned r = v.u + 0x7FFFu + ((v.u >> 16) & 1u);
  return (unsigned short)(r >> 16);
}

// tanh via single exp: tanh(x) = (1-e^{-2x})/(1+e^{-2x}); clamp avoids inf-inf NaN
__device__ __forceinline__ float fast_tanh(float x) {
  float e = __expf(fminf(-2.f * x, 80.f));
  return (1.f - e) / (1.f + e);
}

// ---------------- prep: bf16 conversions + tables + control-buffer init ----------------
__global__ void prep_kernel(const float* __restrict__ x, const float* __restrict__ W_ih,
                            const float* __restrict__ time_, short* __restrict__ xb,
                            short* __restrict__ wb, float* __restrict__ dtp,
                            unsigned* __restrict__ flags, unsigned* __restrict__ mflag,
                            unsigned* __restrict__ relay_slot) {
  size_t i = (size_t)blockIdx.x * blockDim.x + threadIdx.x;
  size_t stride = (size_t)gridDim.x * blockDim.x;
  if (i < (size_t)T * INPUT) xb[i] = (short)f2bf(x[i]);
  for (size_t j = i; j < (size_t)FOURH * INPUT; j += stride) wb[j] = (short)f2bf(W_ih[j]);
  if (i < T) dtp[i] = (i >= 2) ? (time_[i - 1] - time_[i - 2]) : 0.0f;
  if (i < NBLK) flags[i] = 0u;
  if (i < 4096) mflag[i] = 0u;          // 8 xcd x 8 chunks, stride-64 dword spread
  if (i < 8) relay_slot[i] = 0xFFFFFFFFu;
}

// ---------------- xg GEMM: C[m][n] = sum_k x[m][k] * W_ih[n][k] + b_ih[n] + b_hh[n] ----
__global__ void __launch_bounds__(256)
gemm_xg(const short* __restrict__ A, const short* __restrict__ B,
        const float* __restrict__ b_ih, const float* __restrict__ b_hh,
        float* __restrict__ xg) {
  int wave = threadIdx.x >> 6;
  int lane = threadIdx.x & 63;
  int bid = blockIdx.x;
  int m0 = (bid & 127) << 4;
  int n0 = ((bid >> 7) << 6) + (wave << 4);
  int r16 = lane & 15, q = lane >> 4;
  const short* ap = A + (size_t)(m0 + r16) * INPUT + q * 8;
  const short* bp = B + (size_t)(n0 + r16) * INPUT + q * 8;
  f32x4_t acc = {0.f, 0.f, 0.f, 0.f};
#pragma unroll 4
  for (int k = 0; k < INPUT; k += 32) {
    bf16x8 av = *(const bf16x8*)(ap + k);
    bf16x8 bv = *(const bf16x8*)(bp + k);
    acc = __builtin_amdgcn_mfma_f32_16x16x32_bf16(av, bv, acc, 0, 0, 0);
  }
  int n = n0 + r16;
  float bias = b_ih[n] + b_hh[n];
#pragma unroll
  for (int r = 0; r < 4; ++r) {
    int m = m0 + q * 4 + r;
    xg[(size_t)m * FOURH + n] = acc[r] + bias;
  }
}

// ---------------- epoch barrier (only every 256 steps, for ring WAR bound) ------------
__device__ __forceinline__ void epoch_bar(unsigned* flags, unsigned e) {
  __syncthreads();
  if (threadIdx.x == 0)
    __hip_atomic_store(&flags[blockIdx.x], e, __ATOMIC_RELEASE, __HIP_MEMORY_SCOPE_AGENT);
  if (threadIdx.x < NBLK) {
    while (__hip_atomic_load(&flags[threadIdx.x], __ATOMIC_RELAXED,
                             __HIP_MEMORY_SCOPE_AGENT) < e) {
    }
  }
  __builtin_amdgcn_fence(__ATOMIC_ACQUIRE, "agent");
  __syncthreads();
}

// ---------------- persistent recurrence: tagged dataflow + per-XCD relay broadcast ----
// 256 blocks x 512 thr (8 waves, 1 block/CU). wave w of block b owns hidden unit
// u = 8b+w. Ring word (8B): hi32 = tag (t+1 for step-t input), lo32 = fp32 h*gamma.
// R14 == R13 (never executed: R12 infra exception, R13 GPU-acquisition timeout).
// Relay design, FAILURE-HARDENED:
//  * per XCD one relay block (atomicCAS elected via s_getreg(HW_REG_XCC_ID)) polls
//    the IF ring with the PROVEN R11 batched poll (8 waves x 2KB), forwards chunks
//    into an XCD-local L2 mirror (plain write-through stores + vmcnt(0) drain),
//    then sets a per-chunk flag (plain volatile store -> L2).
//  * consumers spin on the flag with sc0 (L1-bypass, L2-hit) loads for AT MOST 24
//    rounds; on success: one sc0 dwordx4 mirror read. On timeout: fall back to the
//    proven R11 ring poll for that step. Mixed-mode is safe (ring always carries
//    truth; mirror is only an accelerator) -> no hang is possible.
//  * mirror parity (t&1) WAR: relay overwrites parity p at step t+2 only after ring
//    shows tags t+3, which requires all blocks finished step t+1, hence all step-t
//    mirror reads done. Consumer flag value is bounded to [t+1, t+2] by the same
//    argument, so parity data cannot be overwritten under a satisfied flag.
//  * cross-dispatch staleness: prep re-zeroes mflag; kernel-boundary cache
//    flush/invalidate makes the zeros visible to first-step sc0 reads.
// LOAD-BEARING (R9/R10): batched unconditional polls; BOTH per-step barriers.
__global__ void __launch_bounds__(512, 2)
lstm_rec(const float* __restrict__ xg, const float* __restrict__ W_hh,
         const float* __restrict__ decay_w, const float* __restrict__ decay_b,
         const float* __restrict__ h0, const float* __restrict__ c0,
         const float* __restrict__ dtp, float* __restrict__ hs,
         unsigned long long* ring, unsigned* flags, float* mirF,
         unsigned* mflag, unsigned* relay_slot) {
  const int wave = threadIdx.x >> 6;
  const int lane = threadIdx.x & 63;
  const int u = (blockIdx.x << 3) + wave;
  __shared__ __align__(16) float lh[H];
  __shared__ int s_xcd, s_isrelay;

  if (threadIdx.x == 0) {
    unsigned xcc;
    asm volatile("s_getreg_b32 %0, hwreg(HW_REG_XCC_ID)" : "=s"(xcc));
    xcc &= 7u;
    s_xcd = (int)xcc;
    unsigned old = atomicCAS(&relay_slot[xcc], 0xFFFFFFFFu, (unsigned)blockIdx.x);
    s_isrelay = (old == 0xFFFFFFFFu) ? 1 : 0;
  }

  // weights: wreg[g][4p+e] = W_hh[g*H+u][256p + 4*lane + e]  (coalesced b128 loads)
  float wreg[4][32];
#pragma unroll
  for (int g = 0; g < 4; ++g) {
    const float* wr = W_hh + (size_t)(g * H + u) * H + (lane << 2);
#pragma unroll
    for (int p = 0; p < 8; ++p)
      *(f32x4_t*)&wreg[g][p << 2] = *(const f32x4_t*)(wr + (p << 8));
  }
  const float dw = decay_w[u], db = decay_b[u];
  float c = c0[u];  // uniform across all lanes (redundant compute, no divergence)
  if (lane == 0) {
    union { float f; unsigned u; } hv; hv.f = h0[u];  // gamma[0] = 1, tag = 1
    __hip_atomic_store(&ring[u], (1ull << 32) | hv.u, __ATOMIC_RELAXED,
                       __HIP_MEMORY_SCOPE_AGENT);
  }
  __syncthreads();
  const int myxcd = s_xcd;
  const bool isrelay = (s_isrelay != 0);

  for (int t = 0; t < T; ++t) {
    if ((t & 255) == 0 && t) epoch_bar(flags, (unsigned)(t >> 8));

    // off-critical-path prefetch: lane e<4 loads gate-e input; lane 0 next gamma
    float xv = 0.f, gam = 0.f;
    if (lane < 4) xv = xg[(size_t)t * FOURH + (size_t)lane * H + u];
    if (lane == 0 && t + 1 < T) gam = __expf(-fmaxf(0.f, dtp[t + 1] * dw + db));

    const unsigned want = (unsigned)t + 1u;
    if (isrelay) {
      // relay: PROVEN R11 batched poll of own 1/8 slice of the IF ring
      unsigned long long* sp =
          ring + (((size_t)(t & (RING - 1)) << 11) | (unsigned)((wave << 8) + lane));
      unsigned long long w0, w1, w2, w3;
      for (;;) {
        w0 = __hip_atomic_load(sp,       __ATOMIC_RELAXED, __HIP_MEMORY_SCOPE_AGENT);
        w1 = __hip_atomic_load(sp + 64,  __ATOMIC_RELAXED, __HIP_MEMORY_SCOPE_AGENT);
        w2 = __hip_atomic_load(sp + 128, __ATOMIC_RELAXED, __HIP_MEMORY_SCOPE_AGENT);
        w3 = __hip_atomic_load(sp + 192, __ATOMIC_RELAXED, __HIP_MEMORY_SCOPE_AGENT);
        int bad = ((unsigned)(w0 >> 32) != want) | ((unsigned)(w1 >> 32) != want) |
                  ((unsigned)(w2 >> 32) != want) | ((unsigned)(w3 >> 32) != want);
        if (!__any(bad)) break;
      }
      union { unsigned u; float f; } e0, e1, e2, e3;
      e0.u = (unsigned)w0; e1.u = (unsigned)w1; e2.u = (unsigned)w2; e3.u = (unsigned)w3;
      // mirror forward: plain write-through stores into local L2, drain, then flag
      float* mp = mirF + (((size_t)myxcd << 12) |
                          (unsigned)(((t & 1) << 11) | (wave << 8) | lane));
      mp[0] = e0.f; mp[64] = e1.f; mp[128] = e2.f; mp[192] = e3.f;
      asm volatile("s_waitcnt vmcnt(0)" ::: "memory");
      if (lane == 0) {
        volatile unsigned* fgp = mflag + ((myxcd << 9) | (wave << 6));
        *fgp = want;
      }
      // stage own chunk into LDS (identity layout lh[i] = h_i)
      float* lw = lh + (wave << 8) + lane;
      lw[0] = e0.f; lw[64] = e1.f; lw[128] = e2.f; lw[192] = e3.f;
    } else {
      // consumer: bounded sc0 flag spin (L2-hit), fallback to proven ring poll
      const unsigned* fgp = mflag + ((myxcd << 9) | (wave << 6));
      unsigned f = 0;
#pragma unroll 1
      for (int r = 0; r < 24; ++r) {
        asm volatile("global_load_dword %0, %1, off sc0\n\ts_waitcnt vmcnt(0)"
                     : "=v"(f) : "v"(fgp) : "memory");
        if (f >= want) break;
      }
      if (f >= want) {
        const float* mp = mirF + (((size_t)myxcd << 12) |
                                  (unsigned)(((t & 1) << 11) | (wave << 8) | (lane << 2)));
        f32x4_t h4;
        asm volatile("global_load_dwordx4 %0, %1, off sc0\n\ts_waitcnt vmcnt(0)"
                     : "=v"(h4) : "v"(mp) : "memory");
        *(f32x4_t*)(lh + (wave << 8) + (lane << 2)) = h4;
      } else {
        // fallback: PROVEN R11 ring poll (cannot hang; ring always has the data)
        unsigned long long* sp =
            ring + (((size_t)(t & (RING - 1)) << 11) | (unsigned)((wave << 8) + lane));
        unsigned long long w0, w1, w2, w3;
        for (;;) {
          w0 = __hip_atomic_load(sp,       __ATOMIC_RELAXED, __HIP_MEMORY_SCOPE_AGENT);
          w1 = __hip_atomic_load(sp + 64,  __ATOMIC_RELAXED, __HIP_MEMORY_SCOPE_AGENT);
          w2 = __hip_atomic_load(sp + 128, __ATOMIC_RELAXED, __HIP_MEMORY_SCOPE_AGENT);
          w3 = __hip_atomic_load(sp + 192, __ATOMIC_RELAXED, __HIP_MEMORY_SCOPE_AGENT);
          int bad = ((unsigned)(w0 >> 32) != want) | ((unsigned)(w1 >> 32) != want) |
                    ((unsigned)(w2 >> 32) != want) | ((unsigned)(w3 >> 32) != want);
          if (!__any(bad)) break;
        }
        float* lw = lh + (wave << 8) + lane;
        union { unsigned u; float f; } v;
        v.u = (unsigned)w0; lw[0]   = v.f;
        v.u = (unsigned)w1; lw[64]  = v.f;
        v.u = (unsigned)w2; lw[128] = v.f;
        v.u = (unsigned)w3; lw[192] = v.f;
      }
    }
    __syncthreads();

    float a0 = 0.f, a1 = 0.f, a2 = 0.f, a3 = 0.f;
#pragma unroll
    for (int p = 0; p < 8; ++p) {
      f32x4_t h4 = *(const f32x4_t*)(lh + (p << 8) + (lane << 2));  // conflict-free b128
#pragma unroll
      for (int e = 0; e < 4; ++e) {
        float h = h4[e];
        a0 += wreg[0][(p << 2) + e] * h;
        a1 += wreg[1][(p << 2) + e] * h;
        a2 += wreg[2][(p << 2) + e] * h;
        a3 += wreg[3][(p << 2) + e] * h;
      }
    }
#pragma unroll
    for (int s = 32; s >= 1; s >>= 1) {
      a0 += __shfl_xor(a0, s);
      a1 += __shfl_xor(a1, s);
      a2 += __shfl_xor(a2, s);
      a3 += __shfl_xor(a3, s);
    }

    // activations parallelized: lane e<4 does one transcendental (sigma form:
    // tanh(x) = 2*sigma(2x)-1), 4 shfl broadcasts, then uniform c/h on all lanes.
    {
      float pre = ((lane == 0) ? a0 : (lane == 1) ? a1 : (lane == 2) ? a2 : a3) + xv;
      float ps = (lane == 2) ? 2.f * pre : pre;
      float sg = 1.f / (1.f + __expf(-ps));
      float act = (lane == 2) ? 2.f * sg - 1.f : sg;
      float iv = __shfl(act, 0), fv = __shfl(act, 1), gv = __shfl(act, 2),
            ov = __shfl(act, 3);
      c = fv * c + iv * gv;
      float h = ov * fast_tanh(c);
      if (lane == 0 && t + 1 < T) {  // publish: the chip-wide critical path
        union { float f; unsigned u; } hv; hv.f = h * gam;
        size_t slot = (size_t)((t + 1) & (RING - 1)) << 11;
        __hip_atomic_store(&ring[slot | (unsigned)u],
                           (((unsigned long long)(t + 2)) << 32) | hv.u,
                           __ATOMIC_RELAXED, __HIP_MEMORY_SCOPE_AGENT);
      }
      if (lane == 1) hs[(size_t)t * H + u] = h;  // pristine fp32 h for attention
    }
    __syncthreads();  // keep publish ahead of next step's poll flood (see R7)
  }
}

// ---------------- attention pooling ----------------
__global__ void attn_k(const float* __restrict__ hs, float* __restrict__ attn) {
  int t = blockIdx.x;
  const float* row = hs + (size_t)t * H;
  const float* hf = hs + (size_t)(T - 1) * H;
  float s = 0.f;
  for (int i = threadIdx.x; i < H; i += 256) s += row[i] * hf[i];
#pragma unroll
  for (int o = 32; o; o >>= 1) s += __shfl_down(s, o);
  __shared__ float wsum[4];
  if ((threadIdx.x & 63) == 0) wsum[threadIdx.x >> 6] = s;
  __syncthreads();
  if (threadIdx.x == 0) attn[t] = wsum[0] + wsum[1] + wsum[2] + wsum[3];
}

__global__ void softmax_k(float* __restrict__ a) {
  int tid = threadIdx.x;
  __shared__ float red[16];
  __shared__ float bcast;
  float m = -1e30f;
  for (int i = tid; i < T; i += 1024) m = fmaxf(m, a[i]);
#pragma unroll
  for (int o = 32; o; o >>= 1) m = fmaxf(m, __shfl_xor(m, o));
  if ((tid & 63) == 0) red[tid >> 6] = m;
  __syncthreads();
  if (tid == 0) {
    float mm = red[0];
    for (int i = 1; i < 16; ++i) mm = fmaxf(mm, red[i]);
    bcast = mm;
  }
  __syncthreads();
  float M = bcast, s = 0.f;
  for (int i = tid; i < T; i += 1024) { float e = __expf(a[i] - M); a[i] = e; s += e; }
#pragma unroll
  for (int o = 32; o; o >>= 1) s += __shfl_xor(s, o);
  if ((tid & 63) == 0) red[tid >> 6] = s;
  __syncthreads();
  if (tid == 0) {
    float ss = 0.f;
    for (int i = 0; i < 16; ++i) ss += red[i];
    bcast = 1.f / ss;
  }
  __syncthreads();
  float inv = bcast;
  for (int i = tid; i < T; i += 1024) a[i] *= inv;
}

__global__ void ctx_k(const float* __restrict__ hs, const float* __restrict__ w,
                      float* __restrict__ out) {
  int h = (blockIdx.x << 8) + threadIdx.x;
  int t0 = blockIdx.y << 6;
  float acc = 0.f;
  for (int t = t0; t < t0 + 64; ++t) acc += w[t] * hs[(size_t)t * H + h];
  atomicAdd(&out[h], acc);
}

// ---------------- launch ----------------
extern "C" void kernel_launch(void* const* d_in, const int* in_sizes, int n_in,
                              void* d_out, int out_size, void* d_ws, size_t ws_size,
                              hipStream_t stream) {
  const float* x       = (const float*)d_in[0];
  const float* time_   = (const float*)d_in[1];
  const float* W_ih    = (const float*)d_in[2];
  const float* W_hh    = (const float*)d_in[3];
  const float* b_ih    = (const float*)d_in[4];
  const float* b_hh    = (const float*)d_in[5];
  const float* decay_w = (const float*)d_in[6];
  const float* decay_b = (const float*)d_in[7];
  const float* h0      = (const float*)d_in[8];
  const float* c0      = (const float*)d_in[9];

  char* ws = (char*)d_ws;
  float*    xg   = (float*)ws;                          // 64 MB  [T][4H]
  float*    hs   = (float*)(ws + (64u << 20));          // 16 MB  [T][H]
  short*    xb   = (short*)(ws + (80u << 20));          // 4 MB
  short*    wb   = (short*)(ws + (84u << 20));          // 16 MB
  unsigned long long* ring = (unsigned long long*)(ws + (100u << 20)); // 8 MB [RING][H]
  float*    dtp  = (float*)(ws + (108u << 20));                    // 8 KB
  float*    attn = dtp + T;                                        // 8 KB
  unsigned* flags = (unsigned*)(attn + T);                         // 1 KB
  float*    mirF = (float*)(ws + (108u << 20) + (32u << 10));      // 128 KB [8][2][2048]
  unsigned* mflag = (unsigned*)(ws + (108u << 20) + (160u << 10)); // 16 KB [8][8] x64
  unsigned* relay_slot = (unsigned*)(ws + (108u << 20) + (176u << 10)); // 32 B

  prep_kernel<<<8192, 256, 0, stream>>>(x, W_ih, time_, xb, wb, dtp, flags, mflag,
                                        relay_slot);

  gemm_xg<<<16384, 256, 0, stream>>>(xb, wb, b_ih, b_hh, xg);

  {
    void* args[] = {&xg, (void*)&W_hh, (void*)&decay_w, (void*)&decay_b,
                    (void*)&h0, (void*)&c0, &dtp, &hs, &ring, &flags,
                    &mirF, &mflag, &relay_slot};
    (void)hipLaunchCooperativeKernel((void*)lstm_rec, dim3(NBLK), dim3(512), args, 0, stream);
  }

  attn_k<<<T, 256, 0, stream>>>(hs, attn);
  softmax_k<<<1, 1024, 0, stream>>>(attn);
  (void)hipMemsetAsync(d_out, 0, out_size * sizeof(float), stream);
  ctx_k<<<dim3(H / 256, T / 64), 256, 0, stream>>>(hs, attn, (float*)d_out);
}

// Round 7
// 7806.255 us; speedup vs baseline: 1.3515x; 1.3515x over previous
//
#include <hip/hip_runtime.h>
#include <hip/hip_bf16.h>

#define H 2048
#define T 2048
#define INPUT 1024
#define FOURH 8192
#define NBLK 256
#define RING 512  // ring slots; epoch barrier every 256 steps bounds skew < 512

typedef __attribute__((ext_vector_type(8))) short bf16x8;
typedef __attribute__((ext_vector_type(4))) float f32x4_t;

__device__ __forceinline__ unsigned short f2bf(float f) {
  union { float f; unsigned u; } v; v.f = f;
  unsigned r = v.u + 0x7FFFu + ((v.u >> 16) & 1u);
  return (unsigned short)(r >> 16);
}

// tanh via single exp: tanh(x) = (1-e^{-2x})/(1+e^{-2x}); clamp avoids inf-inf NaN
__device__ __forceinline__ float fast_tanh(float x) {
  float e = __expf(fminf(-2.f * x, 80.f));
  return (1.f - e) / (1.f + e);
}

// ---------------- prep: bf16 conversions + dt_prev table + flag init ----------------
__global__ void prep_kernel(const float* __restrict__ x, const float* __restrict__ W_ih,
                            const float* __restrict__ time_, short* __restrict__ xb,
                            short* __restrict__ wb, float* __restrict__ dtp,
                            unsigned* __restrict__ flags) {
  size_t i = (size_t)blockIdx.x * blockDim.x + threadIdx.x;
  size_t stride = (size_t)gridDim.x * blockDim.x;
  if (i < (size_t)T * INPUT) xb[i] = (short)f2bf(x[i]);
  for (size_t j = i; j < (size_t)FOURH * INPUT; j += stride) wb[j] = (short)f2bf(W_ih[j]);
  if (i < T) dtp[i] = (i >= 2) ? (time_[i - 1] - time_[i - 2]) : 0.0f;
  if (i < NBLK) flags[i] = 0u;
}

// ---------------- xg GEMM: C[m][n] = sum_k x[m][k] * W_ih[n][k] + b_ih[n] + b_hh[n] ----
__global__ void __launch_bounds__(256)
gemm_xg(const short* __restrict__ A, const short* __restrict__ B,
        const float* __restrict__ b_ih, const float* __restrict__ b_hh,
        float* __restrict__ xg) {
  int wave = threadIdx.x >> 6;
  int lane = threadIdx.x & 63;
  int bid = blockIdx.x;
  int m0 = (bid & 127) << 4;
  int n0 = ((bid >> 7) << 6) + (wave << 4);
  int r16 = lane & 15, q = lane >> 4;
  const short* ap = A + (size_t)(m0 + r16) * INPUT + q * 8;
  const short* bp = B + (size_t)(n0 + r16) * INPUT + q * 8;
  f32x4_t acc = {0.f, 0.f, 0.f, 0.f};
#pragma unroll 4
  for (int k = 0; k < INPUT; k += 32) {
    bf16x8 av = *(const bf16x8*)(ap + k);
    bf16x8 bv = *(const bf16x8*)(bp + k);
    acc = __builtin_amdgcn_mfma_f32_16x16x32_bf16(av, bv, acc, 0, 0, 0);
  }
  int n = n0 + r16;
  float bias = b_ih[n] + b_hh[n];
#pragma unroll
  for (int r = 0; r < 4; ++r) {
    int m = m0 + q * 4 + r;
    xg[(size_t)m * FOURH + n] = acc[r] + bias;
  }
}

// ---------------- epoch barrier (only every 256 steps, for ring WAR bound) ------------
__device__ __forceinline__ void epoch_bar(unsigned* flags, unsigned e) {
  __syncthreads();
  if (threadIdx.x == 0)
    __hip_atomic_store(&flags[blockIdx.x], e, __ATOMIC_RELEASE, __HIP_MEMORY_SCOPE_AGENT);
  if (threadIdx.x < NBLK) {
    while (__hip_atomic_load(&flags[threadIdx.x], __ATOMIC_RELAXED,
                             __HIP_MEMORY_SCOPE_AGENT) < e) {
    }
  }
  __builtin_amdgcn_fence(__ATOMIC_ACQUIRE, "agent");
  __syncthreads();
}

// ---------------- persistent recurrence: tagged 8B dataflow (R11 base + sleep poll) ---
// 256 blocks x 512 thr (8 waves, 1 block/CU). wave w of block b owns hidden unit
// u = 8b+w: gate rows {u, H+u, 2H+u, 3H+u}; lane l owns columns {256p+4l+e}.
// Transport (8B): hi32 = tag (t+1 for step-t input), lo32 = bits(h*gamma) fp32.
// Poll: wave w covers slot words [256w,256w+256); lane l loads 4x8B stride-64,
// batched + unconditional (R9 lesson), with BOTH per-step barriers (R10 lesson).
// R15 change (single-variable): s_sleep(8) (~512cy) after each MISSED poll round.
// Theory: each ring line is re-read by 256 waves at ~400cy period while 2048
// publishes serialize into the same lines; the spin flood's service time sets the
// ~7000cy step (R10: more flood -> 2.1x worse; R11: shorter dep chain -> no change;
// R14: relay detour -> falsified). Halving the poll rate gives publishes quiet
// windows at ~250cy average detection-quantization cost.
__global__ void __launch_bounds__(512, 2)
lstm_rec(const float* __restrict__ xg, const float* __restrict__ W_hh,
         const float* __restrict__ decay_w, const float* __restrict__ decay_b,
         const float* __restrict__ h0, const float* __restrict__ c0,
         const float* __restrict__ dtp, float* __restrict__ hs,
         unsigned long long* ring, unsigned* flags) {
  const int wave = threadIdx.x >> 6;
  const int lane = threadIdx.x & 63;
  const int u = (blockIdx.x << 3) + wave;
  __shared__ __align__(16) float lh[H];

  // weights: wreg[g][4p+e] = W_hh[g*H+u][256p + 4*lane + e]  (coalesced b128 loads)
  float wreg[4][32];
#pragma unroll
  for (int g = 0; g < 4; ++g) {
    const float* wr = W_hh + (size_t)(g * H + u) * H + (lane << 2);
#pragma unroll
    for (int p = 0; p < 8; ++p)
      *(f32x4_t*)&wreg[g][p << 2] = *(const f32x4_t*)(wr + (p << 8));
  }
  const float dw = decay_w[u], db = decay_b[u];
  float c = c0[u];  // uniform across all lanes (redundant compute, no divergence)
  if (lane == 0) {
    union { float f; unsigned u; } hv; hv.f = h0[u];  // gamma[0] = 1, tag = 1
    __hip_atomic_store(&ring[u], (1ull << 32) | hv.u, __ATOMIC_RELAXED,
                       __HIP_MEMORY_SCOPE_AGENT);
  }

  for (int t = 0; t < T; ++t) {
    if ((t & 255) == 0 && t) epoch_bar(flags, (unsigned)(t >> 8));

    // off-critical-path prefetch: lane e<4 loads gate-e input; lane 0 next gamma
    float xv = 0.f, gam = 0.f;
    if (lane < 4) xv = xg[(size_t)t * FOURH + (size_t)lane * H + u];
    if (lane == 0 && t + 1 < T) gam = __expf(-fmaxf(0.f, dtp[t + 1] * dw + db));

    // coalesced poll of this wave's 1/8 slice (4 x 8B per lane, lane-contiguous),
    // with ~512cy sleep between missed rounds (R15: flood-rate / 2.3)
    const unsigned want = (unsigned)t + 1u;
    unsigned long long* sp =
        ring + (((size_t)(t & (RING - 1)) << 11) | (unsigned)((wave << 8) + lane));
    unsigned long long w0, w1, w2, w3;
    for (;;) {
      w0 = __hip_atomic_load(sp,       __ATOMIC_RELAXED, __HIP_MEMORY_SCOPE_AGENT);
      w1 = __hip_atomic_load(sp + 64,  __ATOMIC_RELAXED, __HIP_MEMORY_SCOPE_AGENT);
      w2 = __hip_atomic_load(sp + 128, __ATOMIC_RELAXED, __HIP_MEMORY_SCOPE_AGENT);
      w3 = __hip_atomic_load(sp + 192, __ATOMIC_RELAXED, __HIP_MEMORY_SCOPE_AGENT);
      int bad = ((unsigned)(w0 >> 32) != want) | ((unsigned)(w1 >> 32) != want) |
                ((unsigned)(w2 >> 32) != want) | ((unsigned)(w3 >> 32) != want);
      if (!__any(bad)) break;
      __builtin_amdgcn_s_sleep(8);
    }
    // dedup through LDS, identity layout lh[i] = h_i
    {
      float* lw = lh + (wave << 8) + lane;
      union { unsigned u; float f; } v;
      v.u = (unsigned)w0; lw[0]   = v.f;
      v.u = (unsigned)w1; lw[64]  = v.f;
      v.u = (unsigned)w2; lw[128] = v.f;
      v.u = (unsigned)w3; lw[192] = v.f;
    }
    __syncthreads();

    float a0 = 0.f, a1 = 0.f, a2 = 0.f, a3 = 0.f;
#pragma unroll
    for (int p = 0; p < 8; ++p) {
      f32x4_t h4 = *(const f32x4_t*)(lh + (p << 8) + (lane << 2));  // conflict-free b128
#pragma unroll
      for (int e = 0; e < 4; ++e) {
        float h = h4[e];
        a0 += wreg[0][(p << 2) + e] * h;
        a1 += wreg[1][(p << 2) + e] * h;
        a2 += wreg[2][(p << 2) + e] * h;
        a3 += wreg[3][(p << 2) + e] * h;
      }
    }
#pragma unroll
    for (int s = 32; s >= 1; s >>= 1) {
      a0 += __shfl_xor(a0, s);
      a1 += __shfl_xor(a1, s);
      a2 += __shfl_xor(a2, s);
      a3 += __shfl_xor(a3, s);
    }

    // activations parallelized: lane e<4 does one transcendental (sigma form:
    // tanh(x) = 2*sigma(2x)-1), 4 shfl broadcasts, then uniform c/h on all lanes.
    {
      float pre = ((lane == 0) ? a0 : (lane == 1) ? a1 : (lane == 2) ? a2 : a3) + xv;
      float ps = (lane == 2) ? 2.f * pre : pre;
      float sg = 1.f / (1.f + __expf(-ps));
      float act = (lane == 2) ? 2.f * sg - 1.f : sg;
      float iv = __shfl(act, 0), fv = __shfl(act, 1), gv = __shfl(act, 2),
            ov = __shfl(act, 3);
      c = fv * c + iv * gv;
      float h = ov * fast_tanh(c);
      if (lane == 0 && t + 1 < T) {  // publish: the chip-wide critical path
        union { float f; unsigned u; } hv; hv.f = h * gam;
        size_t slot = (size_t)((t + 1) & (RING - 1)) << 11;
        __hip_atomic_store(&ring[slot | (unsigned)u],
                           (((unsigned long long)(t + 2)) << 32) | hv.u,
                           __ATOMIC_RELAXED, __HIP_MEMORY_SCOPE_AGENT);
      }
      if (lane == 1) hs[(size_t)t * H + u] = h;  // pristine fp32 h for attention
    }
    __syncthreads();  // keep publish ahead of next step's poll flood (see R7)
  }
}

// ---------------- attention pooling ----------------
__global__ void attn_k(const float* __restrict__ hs, float* __restrict__ attn) {
  int t = blockIdx.x;
  const float* row = hs + (size_t)t * H;
  const float* hf = hs + (size_t)(T - 1) * H;
  float s = 0.f;
  for (int i = threadIdx.x; i < H; i += 256) s += row[i] * hf[i];
#pragma unroll
  for (int o = 32; o; o >>= 1) s += __shfl_down(s, o);
  __shared__ float wsum[4];
  if ((threadIdx.x & 63) == 0) wsum[threadIdx.x >> 6] = s;
  __syncthreads();
  if (threadIdx.x == 0) attn[t] = wsum[0] + wsum[1] + wsum[2] + wsum[3];
}

__global__ void softmax_k(float* __restrict__ a) {
  int tid = threadIdx.x;
  __shared__ float red[16];
  __shared__ float bcast;
  float m = -1e30f;
  for (int i = tid; i < T; i += 1024) m = fmaxf(m, a[i]);
#pragma unroll
  for (int o = 32; o; o >>= 1) m = fmaxf(m, __shfl_xor(m, o));
  if ((tid & 63) == 0) red[tid >> 6] = m;
  __syncthreads();
  if (tid == 0) {
    float mm = red[0];
    for (int i = 1; i < 16; ++i) mm = fmaxf(mm, red[i]);
    bcast = mm;
  }
  __syncthreads();
  float M = bcast, s = 0.f;
  for (int i = tid; i < T; i += 1024) { float e = __expf(a[i] - M); a[i] = e; s += e; }
#pragma unroll
  for (int o = 32; o; o >>= 1) s += __shfl_xor(s, o);
  if ((tid & 63) == 0) red[tid >> 6] = s;
  __syncthreads();
  if (tid == 0) {
    float ss = 0.f;
    for (int i = 0; i < 16; ++i) ss += red[i];
    bcast = 1.f / ss;
  }
  __syncthreads();
  float inv = bcast;
  for (int i = tid; i < T; i += 1024) a[i] *= inv;
}

__global__ void ctx_k(const float* __restrict__ hs, const float* __restrict__ w,
                      float* __restrict__ out) {
  int h = (blockIdx.x << 8) + threadIdx.x;
  int t0 = blockIdx.y << 6;
  float acc = 0.f;
  for (int t = t0; t < t0 + 64; ++t) acc += w[t] * hs[(size_t)t * H + h];
  atomicAdd(&out[h], acc);
}

// ---------------- launch ----------------
extern "C" void kernel_launch(void* const* d_in, const int* in_sizes, int n_in,
                              void* d_out, int out_size, void* d_ws, size_t ws_size,
                              hipStream_t stream) {
  const float* x       = (const float*)d_in[0];
  const float* time_   = (const float*)d_in[1];
  const float* W_ih    = (const float*)d_in[2];
  const float* W_hh    = (const float*)d_in[3];
  const float* b_ih    = (const float*)d_in[4];
  const float* b_hh    = (const float*)d_in[5];
  const float* decay_w = (const float*)d_in[6];
  const float* decay_b = (const float*)d_in[7];
  const float* h0      = (const float*)d_in[8];
  const float* c0      = (const float*)d_in[9];

  char* ws = (char*)d_ws;
  float*    xg   = (float*)ws;                          // 64 MB  [T][4H]
  float*    hs   = (float*)(ws + (64u << 20));          // 16 MB  [T][H]
  short*    xb   = (short*)(ws + (80u << 20));          // 4 MB
  short*    wb   = (short*)(ws + (84u << 20));          // 16 MB
  unsigned long long* ring = (unsigned long long*)(ws + (100u << 20)); // 8 MB [RING][H]
  float*    dtp  = (float*)(ws + (108u << 20));
  float*    attn = dtp + T;
  unsigned* flags = (unsigned*)(attn + T);

  prep_kernel<<<8192, 256, 0, stream>>>(x, W_ih, time_, xb, wb, dtp, flags);

  gemm_xg<<<16384, 256, 0, stream>>>(xb, wb, b_ih, b_hh, xg);

  {
    void* args[] = {&xg, (void*)&W_hh, (void*)&decay_w, (void*)&decay_b,
                    (void*)&h0, (void*)&c0, &dtp, &hs, &ring, &flags};
    (void)hipLaunchCooperativeKernel((void*)lstm_rec, dim3(NBLK), dim3(512), args, 0, stream);
  }

  attn_k<<<T, 256, 0, stream>>>(hs, attn);
  softmax_k<<<1, 1024, 0, stream>>>(attn);
  (void)hipMemsetAsync(d_out, 0, out_size * sizeof(float), stream);
  ctx_k<<<dim3(H / 256, T / 64), 256, 0, stream>>>(hs, attn, (float*)d_out);
}

// Round 8
// 6987.302 us; speedup vs baseline: 1.5099x; 1.1172x over previous
//
#include <hip/hip_runtime.h>
#include <hip/hip_bf16.h>

#define H 2048
#define T 2048
#define INPUT 1024
#define FOURH 8192
#define NBLK 256
#define RING 512  // ring slots; epoch barrier every 256 steps bounds skew < 512

typedef __attribute__((ext_vector_type(8))) short bf16x8;
typedef __attribute__((ext_vector_type(4))) float f32x4_t;

__device__ __forceinline__ unsigned short f2bf(float f) {
  union { float f; unsigned u; } v; v.f = f;
  unsigned r = v.u + 0x7FFFu + ((v.u >> 16) & 1u);
  return (unsigned short)(r >> 16);
}

// tanh via single exp: tanh(x) = (1-e^{-2x})/(1+e^{-2x}); clamp avoids inf-inf NaN
__device__ __forceinline__ float fast_tanh(float x) {
  float e = __expf(fminf(-2.f * x, 80.f));
  return (1.f - e) / (1.f + e);
}

// ---------------- prep: bf16 conversions + dt_prev table + flag init ----------------
__global__ void prep_kernel(const float* __restrict__ x, const float* __restrict__ W_ih,
                            const float* __restrict__ time_, short* __restrict__ xb,
                            short* __restrict__ wb, float* __restrict__ dtp,
                            unsigned* __restrict__ flags) {
  size_t i = (size_t)blockIdx.x * blockDim.x + threadIdx.x;
  size_t stride = (size_t)gridDim.x * blockDim.x;
  if (i < (size_t)T * INPUT) xb[i] = (short)f2bf(x[i]);
  for (size_t j = i; j < (size_t)FOURH * INPUT; j += stride) wb[j] = (short)f2bf(W_ih[j]);
  if (i < T) dtp[i] = (i >= 2) ? (time_[i - 1] - time_[i - 2]) : 0.0f;
  if (i < NBLK) flags[i] = 0u;
}

// ---------------- xg GEMM: C[m][n] = sum_k x[m][k] * W_ih[n][k] + b_ih[n] + b_hh[n] ----
__global__ void __launch_bounds__(256)
gemm_xg(const short* __restrict__ A, const short* __restrict__ B,
        const float* __restrict__ b_ih, const float* __restrict__ b_hh,
        float* __restrict__ xg) {
  int wave = threadIdx.x >> 6;
  int lane = threadIdx.x & 63;
  int bid = blockIdx.x;
  int m0 = (bid & 127) << 4;
  int n0 = ((bid >> 7) << 6) + (wave << 4);
  int r16 = lane & 15, q = lane >> 4;
  const short* ap = A + (size_t)(m0 + r16) * INPUT + q * 8;
  const short* bp = B + (size_t)(n0 + r16) * INPUT + q * 8;
  f32x4_t acc = {0.f, 0.f, 0.f, 0.f};
#pragma unroll 4
  for (int k = 0; k < INPUT; k += 32) {
    bf16x8 av = *(const bf16x8*)(ap + k);
    bf16x8 bv = *(const bf16x8*)(bp + k);
    acc = __builtin_amdgcn_mfma_f32_16x16x32_bf16(av, bv, acc, 0, 0, 0);
  }
  int n = n0 + r16;
  float bias = b_ih[n] + b_hh[n];
#pragma unroll
  for (int r = 0; r < 4; ++r) {
    int m = m0 + q * 4 + r;
    xg[(size_t)m * FOURH + n] = acc[r] + bias;
  }
}

// ---------------- epoch barrier (only every 256 steps, for ring WAR bound) ------------
__device__ __forceinline__ void epoch_bar(unsigned* flags, unsigned e) {
  __syncthreads();
  if (threadIdx.x == 0)
    __hip_atomic_store(&flags[blockIdx.x], e, __ATOMIC_RELEASE, __HIP_MEMORY_SCOPE_AGENT);
  if (threadIdx.x < NBLK) {
    while (__hip_atomic_load(&flags[threadIdx.x], __ATOMIC_RELAXED,
                             __HIP_MEMORY_SCOPE_AGENT) < e) {
    }
  }
  __builtin_amdgcn_fence(__ATOMIC_ACQUIRE, "agent");
  __syncthreads();
}

// ---------------- persistent recurrence: tagged 8B dataflow (R11 base) ----------------
// 256 blocks x 512 thr (8 waves, 1 block/CU). wave w of block b owns hidden unit
// u = 8b+w: gate rows {u, H+u, 2H+u, 3H+u}; lane l owns columns {256p+4l+e}.
// Transport (8B): hi32 = tag (t+1 for step-t input), lo32 = bits(h*gamma) fp32.
// Poll: wave w covers slot words [256w,256w+256); lane l loads 4x8B stride-64,
// batched + unconditional + TIGHT (R9: predication lost; R15: s_sleep throttle lost
// +23% -> detection cadence is precious, IF read path not saturated). BOTH per-step
// barriers stay (R10). R14: relay through XCD-L2 mirror falsified.
// R16 change (write side, single variable): COALESCED PUBLISH. Previously 2048
// scattered 8B agent stores/step = 16 independent writers per 128B ring line from
// 16 CUs -> serialized write/merge events + partial-tag-flip wasted poll rounds.
// Now: each wave's lane0 drops its tagged word into LDS staging; the trailing
// __syncthreads doubles as gather barrier; wave 0 lanes 0-7 issue ONE coalesced
// 64B agent store (8 lanes x adjacent 8B). Ring writes 2048 -> 256/step; writers
// per line 16 -> 2; block-granular tag flips. Publish lands ~150cy later (R11
// showed the tail timing is second-order).
__global__ void __launch_bounds__(512, 2)
lstm_rec(const float* __restrict__ xg, const float* __restrict__ W_hh,
         const float* __restrict__ decay_w, const float* __restrict__ decay_b,
         const float* __restrict__ h0, const float* __restrict__ c0,
         const float* __restrict__ dtp, float* __restrict__ hs,
         unsigned long long* ring, unsigned* flags) {
  const int wave = threadIdx.x >> 6;
  const int lane = threadIdx.x & 63;
  const int u = (blockIdx.x << 3) + wave;
  __shared__ __align__(16) float lh[H];
  __shared__ unsigned long long pubst[8];

  // weights: wreg[g][4p+e] = W_hh[g*H+u][256p + 4*lane + e]  (coalesced b128 loads)
  float wreg[4][32];
#pragma unroll
  for (int g = 0; g < 4; ++g) {
    const float* wr = W_hh + (size_t)(g * H + u) * H + (lane << 2);
#pragma unroll
    for (int p = 0; p < 8; ++p)
      *(f32x4_t*)&wreg[g][p << 2] = *(const f32x4_t*)(wr + (p << 8));
  }
  const float dw = decay_w[u], db = decay_b[u];
  float c = c0[u];  // uniform across all lanes (redundant compute, no divergence)
  if (lane == 0) {
    union { float f; unsigned u; } hv; hv.f = h0[u];  // gamma[0] = 1, tag = 1
    __hip_atomic_store(&ring[u], (1ull << 32) | hv.u, __ATOMIC_RELAXED,
                       __HIP_MEMORY_SCOPE_AGENT);
  }

  for (int t = 0; t < T; ++t) {
    if ((t & 255) == 0 && t) epoch_bar(flags, (unsigned)(t >> 8));

    // off-critical-path prefetch: lane e<4 loads gate-e input; lane 0 next gamma
    float xv = 0.f, gam = 0.f;
    if (lane < 4) xv = xg[(size_t)t * FOURH + (size_t)lane * H + u];
    if (lane == 0 && t + 1 < T) gam = __expf(-fmaxf(0.f, dtp[t + 1] * dw + db));

    // coalesced TIGHT poll of this wave's 1/8 slice (4 x 8B per lane, lane-contiguous)
    const unsigned want = (unsigned)t + 1u;
    unsigned long long* sp =
        ring + (((size_t)(t & (RING - 1)) << 11) | (unsigned)((wave << 8) + lane));
    unsigned long long w0, w1, w2, w3;
    for (;;) {
      w0 = __hip_atomic_load(sp,       __ATOMIC_RELAXED, __HIP_MEMORY_SCOPE_AGENT);
      w1 = __hip_atomic_load(sp + 64,  __ATOMIC_RELAXED, __HIP_MEMORY_SCOPE_AGENT);
      w2 = __hip_atomic_load(sp + 128, __ATOMIC_RELAXED, __HIP_MEMORY_SCOPE_AGENT);
      w3 = __hip_atomic_load(sp + 192, __ATOMIC_RELAXED, __HIP_MEMORY_SCOPE_AGENT);
      int bad = ((unsigned)(w0 >> 32) != want) | ((unsigned)(w1 >> 32) != want) |
                ((unsigned)(w2 >> 32) != want) | ((unsigned)(w3 >> 32) != want);
      if (!__any(bad)) break;
    }
    // dedup through LDS, identity layout lh[i] = h_i
    {
      float* lw = lh + (wave << 8) + lane;
      union { unsigned u; float f; } v;
      v.u = (unsigned)w0; lw[0]   = v.f;
      v.u = (unsigned)w1; lw[64]  = v.f;
      v.u = (unsigned)w2; lw[128] = v.f;
      v.u = (unsigned)w3; lw[192] = v.f;
    }
    __syncthreads();

    float a0 = 0.f, a1 = 0.f, a2 = 0.f, a3 = 0.f;
#pragma unroll
    for (int p = 0; p < 8; ++p) {
      f32x4_t h4 = *(const f32x4_t*)(lh + (p << 8) + (lane << 2));  // conflict-free b128
#pragma unroll
      for (int e = 0; e < 4; ++e) {
        float h = h4[e];
        a0 += wreg[0][(p << 2) + e] * h;
        a1 += wreg[1][(p << 2) + e] * h;
        a2 += wreg[2][(p << 2) + e] * h;
        a3 += wreg[3][(p << 2) + e] * h;
      }
    }
#pragma unroll
    for (int s = 32; s >= 1; s >>= 1) {
      a0 += __shfl_xor(a0, s);
      a1 += __shfl_xor(a1, s);
      a2 += __shfl_xor(a2, s);
      a3 += __shfl_xor(a3, s);
    }

    // activations parallelized: lane e<4 does one transcendental (sigma form:
    // tanh(x) = 2*sigma(2x)-1), 4 shfl broadcasts, then uniform c/h on all lanes.
    {
      float pre = ((lane == 0) ? a0 : (lane == 1) ? a1 : (lane == 2) ? a2 : a3) + xv;
      float ps = (lane == 2) ? 2.f * pre : pre;
      float sg = 1.f / (1.f + __expf(-ps));
      float act = (lane == 2) ? 2.f * sg - 1.f : sg;
      float iv = __shfl(act, 0), fv = __shfl(act, 1), gv = __shfl(act, 2),
            ov = __shfl(act, 3);
      c = fv * c + iv * gv;
      float h = ov * fast_tanh(c);
      if (lane == 0) {  // stage tagged publish word in LDS (gathered below)
        union { float f; unsigned u; } hv; hv.f = h * gam;
        pubst[wave] = (((unsigned long long)(t + 2)) << 32) | hv.u;
      }
      if (lane == 1) hs[(size_t)t * H + u] = h;  // pristine fp32 h for attention
    }
    __syncthreads();  // gather barrier; also keeps lh WAR + publish-before-flood order

    // coalesced publish: ONE 64B agent store for the whole block (8 lanes x 8B)
    if (wave == 0 && lane < 8 && t + 1 < T) {
      size_t slot = (size_t)((t + 1) & (RING - 1)) << 11;
      __hip_atomic_store(&ring[slot | (unsigned)((blockIdx.x << 3) + lane)],
                         pubst[lane], __ATOMIC_RELAXED, __HIP_MEMORY_SCOPE_AGENT);
    }
  }
}

// ---------------- attention pooling ----------------
__global__ void attn_k(const float* __restrict__ hs, float* __restrict__ attn) {
  int t = blockIdx.x;
  const float* row = hs + (size_t)t * H;
  const float* hf = hs + (size_t)(T - 1) * H;
  float s = 0.f;
  for (int i = threadIdx.x; i < H; i += 256) s += row[i] * hf[i];
#pragma unroll
  for (int o = 32; o; o >>= 1) s += __shfl_down(s, o);
  __shared__ float wsum[4];
  if ((threadIdx.x & 63) == 0) wsum[threadIdx.x >> 6] = s;
  __syncthreads();
  if (threadIdx.x == 0) attn[t] = wsum[0] + wsum[1] + wsum[2] + wsum[3];
}

__global__ void softmax_k(float* __restrict__ a) {
  int tid = threadIdx.x;
  __shared__ float red[16];
  __shared__ float bcast;
  float m = -1e30f;
  for (int i = tid; i < T; i += 1024) m = fmaxf(m, a[i]);
#pragma unroll
  for (int o = 32; o; o >>= 1) m = fmaxf(m, __shfl_xor(m, o));
  if ((tid & 63) == 0) red[tid >> 6] = m;
  __syncthreads();
  if (tid == 0) {
    float mm = red[0];
    for (int i = 1; i < 16; ++i) mm = fmaxf(mm, red[i]);
    bcast = mm;
  }
  __syncthreads();
  float M = bcast, s = 0.f;
  for (int i = tid; i < T; i += 1024) { float e = __expf(a[i] - M); a[i] = e; s += e; }
#pragma unroll
  for (int o = 32; o; o >>= 1) s += __shfl_xor(s, o);
  if ((tid & 63) == 0) red[tid >> 6] = s;
  __syncthreads();
  if (tid == 0) {
    float ss = 0.f;
    for (int i = 0; i < 16; ++i) ss += red[i];
    bcast = 1.f / ss;
  }
  __syncthreads();
  float inv = bcast;
  for (int i = tid; i < T; i += 1024) a[i] *= inv;
}

__global__ void ctx_k(const float* __restrict__ hs, const float* __restrict__ w,
                      float* __restrict__ out) {
  int h = (blockIdx.x << 8) + threadIdx.x;
  int t0 = blockIdx.y << 6;
  float acc = 0.f;
  for (int t = t0; t < t0 + 64; ++t) acc += w[t] * hs[(size_t)t * H + h];
  atomicAdd(&out[h], acc);
}

// ---------------- launch ----------------
extern "C" void kernel_launch(void* const* d_in, const int* in_sizes, int n_in,
                              void* d_out, int out_size, void* d_ws, size_t ws_size,
                              hipStream_t stream) {
  const float* x       = (const float*)d_in[0];
  const float* time_   = (const float*)d_in[1];
  const float* W_ih    = (const float*)d_in[2];
  const float* W_hh    = (const float*)d_in[3];
  const float* b_ih    = (const float*)d_in[4];
  const float* b_hh    = (const float*)d_in[5];
  const float* decay_w = (const float*)d_in[6];
  const float* decay_b = (const float*)d_in[7];
  const float* h0      = (const float*)d_in[8];
  const float* c0      = (const float*)d_in[9];

  char* ws = (char*)d_ws;
  float*    xg   = (float*)ws;                          // 64 MB  [T][4H]
  float*    hs   = (float*)(ws + (64u << 20));          // 16 MB  [T][H]
  short*    xb   = (short*)(ws + (80u << 20));          // 4 MB
  short*    wb   = (short*)(ws + (84u << 20));          // 16 MB
  unsigned long long* ring = (unsigned long long*)(ws + (100u << 20)); // 8 MB [RING][H]
  float*    dtp  = (float*)(ws + (108u << 20));
  float*    attn = dtp + T;
  unsigned* flags = (unsigned*)(attn + T);

  prep_kernel<<<8192, 256, 0, stream>>>(x, W_ih, time_, xb, wb, dtp, flags);

  gemm_xg<<<16384, 256, 0, stream>>>(xb, wb, b_ih, b_hh, xg);

  {
    void* args[] = {&xg, (void*)&W_hh, (void*)&decay_w, (void*)&decay_b,
                    (void*)&h0, (void*)&c0, &dtp, &hs, &ring, &flags};
    (void)hipLaunchCooperativeKernel((void*)lstm_rec, dim3(NBLK), dim3(512), args, 0, stream);
  }

  attn_k<<<T, 256, 0, stream>>>(hs, attn);
  softmax_k<<<1, 1024, 0, stream>>>(attn);
  (void)hipMemsetAsync(d_out, 0, out_size * sizeof(float), stream);
  ctx_k<<<dim3(H / 256, T / 64), 256, 0, stream>>>(hs, attn, (float*)d_out);
}

// Round 9
// 6282.102 us; speedup vs baseline: 1.6794x; 1.1123x over previous
//
#include <hip/hip_runtime.h>
#include <hip/hip_bf16.h>

#define H 2048
#define T 2048
#define INPUT 1024
#define FOURH 8192
#define NBLK 256
#define RING 512  // ring slots; epoch barrier every 256 steps bounds skew < 512

typedef __attribute__((ext_vector_type(8))) short bf16x8;
typedef __attribute__((ext_vector_type(4))) float f32x4_t;

__device__ __forceinline__ unsigned short f2bf(float f) {
  union { float f; unsigned u; } v; v.f = f;
  unsigned r = v.u + 0x7FFFu + ((v.u >> 16) & 1u);
  return (unsigned short)(r >> 16);
}

// tanh via single exp: tanh(x) = (1-e^{-2x})/(1+e^{-2x}); clamp avoids inf-inf NaN
__device__ __forceinline__ float fast_tanh(float x) {
  float e = __expf(fminf(-2.f * x, 80.f));
  return (1.f - e) / (1.f + e);
}

// ---------------- prep: bf16 conversions + dt_prev table + flag init ----------------
__global__ void prep_kernel(const float* __restrict__ x, const float* __restrict__ W_ih,
                            const float* __restrict__ time_, short* __restrict__ xb,
                            short* __restrict__ wb, float* __restrict__ dtp,
                            unsigned* __restrict__ flags) {
  size_t i = (size_t)blockIdx.x * blockDim.x + threadIdx.x;
  size_t stride = (size_t)gridDim.x * blockDim.x;
  if (i < (size_t)T * INPUT) xb[i] = (short)f2bf(x[i]);
  for (size_t j = i; j < (size_t)FOURH * INPUT; j += stride) wb[j] = (short)f2bf(W_ih[j]);
  if (i < T) dtp[i] = (i >= 2) ? (time_[i - 1] - time_[i - 2]) : 0.0f;
  if (i < NBLK) flags[i] = 0u;
}

// ---------------- xg GEMM: C[m][n] = sum_k x[m][k] * W_ih[n][k] + b_ih[n] + b_hh[n] ----
// R17: 8x m-reuse per B-fragment. Per wave: 128x16 output (8 m-subtiles), one bv
// load feeds 8 MFMAs. Blocks 16384 -> 2048; L2/L3 operand traffic 2.5 GB -> 0.77 GB.
// Per-output FP math identical to R0 gemm (same k-order, same MFMA) -> bitwise same xg.
// 16 consecutive blocks share one B-panel (n-outer / m-inner) for L2 locality.
__global__ void __launch_bounds__(256)
gemm_xg(const short* __restrict__ A, const short* __restrict__ B,
        const float* __restrict__ b_ih, const float* __restrict__ b_hh,
        float* __restrict__ xg) {
  int wave = threadIdx.x >> 6;
  int lane = threadIdx.x & 63;
  int bid = blockIdx.x;
  int m0 = (bid & 15) << 7;                   // 16 m-supertiles of 128 rows
  int n0 = ((bid >> 4) << 6) + (wave << 4);   // 128 n-panels of 64
  int r16 = lane & 15, q = lane >> 4;
  const short* ap = A + (size_t)(m0 + r16) * INPUT + q * 8;
  const short* bp = B + (size_t)(n0 + r16) * INPUT + q * 8;
  f32x4_t acc[8];
#pragma unroll
  for (int s = 0; s < 8; ++s) acc[s] = {0.f, 0.f, 0.f, 0.f};
  for (int k = 0; k < INPUT; k += 32) {
    bf16x8 bv = *(const bf16x8*)(bp + k);
#pragma unroll
    for (int s = 0; s < 8; ++s) {
      bf16x8 av = *(const bf16x8*)(ap + (size_t)(s << 4) * INPUT + k);
      acc[s] = __builtin_amdgcn_mfma_f32_16x16x32_bf16(av, bv, acc[s], 0, 0, 0);
    }
  }
  int n = n0 + r16;
  float bias = b_ih[n] + b_hh[n];
#pragma unroll
  for (int s = 0; s < 8; ++s) {
#pragma unroll
    for (int r = 0; r < 4; ++r) {
      int m = m0 + (s << 4) + q * 4 + r;
      xg[(size_t)m * FOURH + n] = acc[s][r] + bias;
    }
  }
}

// ---------------- epoch barrier (only every 256 steps, for ring WAR bound) ------------
__device__ __forceinline__ void epoch_bar(unsigned* flags, unsigned e) {
  __syncthreads();
  if (threadIdx.x == 0)
    __hip_atomic_store(&flags[blockIdx.x], e, __ATOMIC_RELEASE, __HIP_MEMORY_SCOPE_AGENT);
  if (threadIdx.x < NBLK) {
    while (__hip_atomic_load(&flags[threadIdx.x], __ATOMIC_RELAXED,
                             __HIP_MEMORY_SCOPE_AGENT) < e) {
    }
  }
  __builtin_amdgcn_fence(__ATOMIC_ACQUIRE, "agent");
  __syncthreads();
}

// ---------------- persistent recurrence: tagged 8B dataflow (EXACT R11 — best known) --
// 256 blocks x 512 thr (8 waves, 1 block/CU). wave w of block b owns hidden unit
// u = 8b+w: gate rows {u, H+u, 2H+u, 3H+u}; lane l owns columns {256p+4l+e}.
// Transport (8B): hi32 = tag (t+1 for step-t input), lo32 = bits(h*gamma) fp32.
// Poll: batched + unconditional + TIGHT; BOTH per-step barriers.
// PROTOCOL IS A VERIFIED LOCAL OPTIMUM — six variants all regressed:
//   R9 predicated poll +8% | R10 barrier removal +112% | R14 XCD relay +69%
//   R15 s_sleep throttle +23% | R16 coalesced publish +9% | R11 early-publish ±0
// Step period = IF round-trip x ~2-3 poll rounds + compute/barriers; flood volume
// and write pattern are NOT the binding terms (R15/R16). Do not touch.
__global__ void __launch_bounds__(512, 2)
lstm_rec(const float* __restrict__ xg, const float* __restrict__ W_hh,
         const float* __restrict__ decay_w, const float* __restrict__ decay_b,
         const float* __restrict__ h0, const float* __restrict__ c0,
         const float* __restrict__ dtp, float* __restrict__ hs,
         unsigned long long* ring, unsigned* flags) {
  const int wave = threadIdx.x >> 6;
  const int lane = threadIdx.x & 63;
  const int u = (blockIdx.x << 3) + wave;
  __shared__ __align__(16) float lh[H];

  // weights: wreg[g][4p+e] = W_hh[g*H+u][256p + 4*lane + e]  (coalesced b128 loads)
  float wreg[4][32];
#pragma unroll
  for (int g = 0; g < 4; ++g) {
    const float* wr = W_hh + (size_t)(g * H + u) * H + (lane << 2);
#pragma unroll
    for (int p = 0; p < 8; ++p)
      *(f32x4_t*)&wreg[g][p << 2] = *(const f32x4_t*)(wr + (p << 8));
  }
  const float dw = decay_w[u], db = decay_b[u];
  float c = c0[u];  // uniform across all lanes (redundant compute, no divergence)
  if (lane == 0) {
    union { float f; unsigned u; } hv; hv.f = h0[u];  // gamma[0] = 1, tag = 1
    __hip_atomic_store(&ring[u], (1ull << 32) | hv.u, __ATOMIC_RELAXED,
                       __HIP_MEMORY_SCOPE_AGENT);
  }

  for (int t = 0; t < T; ++t) {
    if ((t & 255) == 0 && t) epoch_bar(flags, (unsigned)(t >> 8));

    // off-critical-path prefetch: lane e<4 loads gate-e input; lane 0 next gamma
    float xv = 0.f, gam = 0.f;
    if (lane < 4) xv = xg[(size_t)t * FOURH + (size_t)lane * H + u];
    if (lane == 0 && t + 1 < T) gam = __expf(-fmaxf(0.f, dtp[t + 1] * dw + db));

    // coalesced TIGHT poll of this wave's 1/8 slice (4 x 8B per lane, lane-contiguous)
    const unsigned want = (unsigned)t + 1u;
    unsigned long long* sp =
        ring + (((size_t)(t & (RING - 1)) << 11) | (unsigned)((wave << 8) + lane));
    unsigned long long w0, w1, w2, w3;
    for (;;) {
      w0 = __hip_atomic_load(sp,       __ATOMIC_RELAXED, __HIP_MEMORY_SCOPE_AGENT);
      w1 = __hip_atomic_load(sp + 64,  __ATOMIC_RELAXED, __HIP_MEMORY_SCOPE_AGENT);
      w2 = __hip_atomic_load(sp + 128, __ATOMIC_RELAXED, __HIP_MEMORY_SCOPE_AGENT);
      w3 = __hip_atomic_load(sp + 192, __ATOMIC_RELAXED, __HIP_MEMORY_SCOPE_AGENT);
      int bad = ((unsigned)(w0 >> 32) != want) | ((unsigned)(w1 >> 32) != want) |
                ((unsigned)(w2 >> 32) != want) | ((unsigned)(w3 >> 32) != want);
      if (!__any(bad)) break;
    }
    // dedup through LDS, identity layout lh[i] = h_i
    {
      float* lw = lh + (wave << 8) + lane;
      union { unsigned u; float f; } v;
      v.u = (unsigned)w0; lw[0]   = v.f;
      v.u = (unsigned)w1; lw[64]  = v.f;
      v.u = (unsigned)w2; lw[128] = v.f;
      v.u = (unsigned)w3; lw[192] = v.f;
    }
    __syncthreads();

    float a0 = 0.f, a1 = 0.f, a2 = 0.f, a3 = 0.f;
#pragma unroll
    for (int p = 0; p < 8; ++p) {
      f32x4_t h4 = *(const f32x4_t*)(lh + (p << 8) + (lane << 2));  // conflict-free b128
#pragma unroll
      for (int e = 0; e < 4; ++e) {
        float h = h4[e];
        a0 += wreg[0][(p << 2) + e] * h;
        a1 += wreg[1][(p << 2) + e] * h;
        a2 += wreg[2][(p << 2) + e] * h;
        a3 += wreg[3][(p << 2) + e] * h;
      }
    }
#pragma unroll
    for (int s = 32; s >= 1; s >>= 1) {
      a0 += __shfl_xor(a0, s);
      a1 += __shfl_xor(a1, s);
      a2 += __shfl_xor(a2, s);
      a3 += __shfl_xor(a3, s);
    }

    // activations parallelized: lane e<4 does one transcendental (sigma form:
    // tanh(x) = 2*sigma(2x)-1), 4 shfl broadcasts, then uniform c/h on all lanes.
    {
      float pre = ((lane == 0) ? a0 : (lane == 1) ? a1 : (lane == 2) ? a2 : a3) + xv;
      float ps = (lane == 2) ? 2.f * pre : pre;
      float sg = 1.f / (1.f + __expf(-ps));
      float act = (lane == 2) ? 2.f * sg - 1.f : sg;
      float iv = __shfl(act, 0), fv = __shfl(act, 1), gv = __shfl(act, 2),
            ov = __shfl(act, 3);
      c = fv * c + iv * gv;
      float h = ov * fast_tanh(c);
      if (lane == 0 && t + 1 < T) {  // publish: the chip-wide critical path
        union { float f; unsigned u; } hv; hv.f = h * gam;
        size_t slot = (size_t)((t + 1) & (RING - 1)) << 11;
        __hip_atomic_store(&ring[slot | (unsigned)u],
                           (((unsigned long long)(t + 2)) << 32) | hv.u,
                           __ATOMIC_RELAXED, __HIP_MEMORY_SCOPE_AGENT);
      }
      if (lane == 1) hs[(size_t)t * H + u] = h;  // pristine fp32 h for attention
    }
    __syncthreads();  // keep publish ahead of next step's poll flood (see R7)
  }
}

// ---------------- attention pooling ----------------
__global__ void attn_k(const float* __restrict__ hs, float* __restrict__ attn) {
  int t = blockIdx.x;
  const float* row = hs + (size_t)t * H;
  const float* hf = hs + (size_t)(T - 1) * H;
  float s = 0.f;
  for (int i = threadIdx.x; i < H; i += 256) s += row[i] * hf[i];
#pragma unroll
  for (int o = 32; o; o >>= 1) s += __shfl_down(s, o);
  __shared__ float wsum[4];
  if ((threadIdx.x & 63) == 0) wsum[threadIdx.x >> 6] = s;
  __syncthreads();
  if (threadIdx.x == 0) attn[t] = wsum[0] + wsum[1] + wsum[2] + wsum[3];
}

__global__ void softmax_k(float* __restrict__ a) {
  int tid = threadIdx.x;
  __shared__ float red[16];
  __shared__ float bcast;
  float m = -1e30f;
  for (int i = tid; i < T; i += 1024) m = fmaxf(m, a[i]);
#pragma unroll
  for (int o = 32; o; o >>= 1) m = fmaxf(m, __shfl_xor(m, o));
  if ((tid & 63) == 0) red[tid >> 6] = m;
  __syncthreads();
  if (tid == 0) {
    float mm = red[0];
    for (int i = 1; i < 16; ++i) mm = fmaxf(mm, red[i]);
    bcast = mm;
  }
  __syncthreads();
  float M = bcast, s = 0.f;
  for (int i = tid; i < T; i += 1024) { float e = __expf(a[i] - M); a[i] = e; s += e; }
#pragma unroll
  for (int o = 32; o; o >>= 1) s += __shfl_xor(s, o);
  if ((tid & 63) == 0) red[tid >> 6] = s;
  __syncthreads();
  if (tid == 0) {
    float ss = 0.f;
    for (int i = 0; i < 16; ++i) ss += red[i];
    bcast = 1.f / ss;
  }
  __syncthreads();
  float inv = bcast;
  for (int i = tid; i < T; i += 1024) a[i] *= inv;
}

__global__ void ctx_k(const float* __restrict__ hs, const float* __restrict__ w,
                      float* __restrict__ out) {
  int h = (blockIdx.x << 8) + threadIdx.x;
  int t0 = blockIdx.y << 6;
  float acc = 0.f;
  for (int t = t0; t < t0 + 64; ++t) acc += w[t] * hs[(size_t)t * H + h];
  atomicAdd(&out[h], acc);
}

// ---------------- launch ----------------
extern "C" void kernel_launch(void* const* d_in, const int* in_sizes, int n_in,
                              void* d_out, int out_size, void* d_ws, size_t ws_size,
                              hipStream_t stream) {
  const float* x       = (const float*)d_in[0];
  const float* time_   = (const float*)d_in[1];
  const float* W_ih    = (const float*)d_in[2];
  const float* W_hh    = (const float*)d_in[3];
  const float* b_ih    = (const float*)d_in[4];
  const float* b_hh    = (const float*)d_in[5];
  const float* decay_w = (const float*)d_in[6];
  const float* decay_b = (const float*)d_in[7];
  const float* h0      = (const float*)d_in[8];
  const float* c0      = (const float*)d_in[9];

  char* ws = (char*)d_ws;
  float*    xg   = (float*)ws;                          // 64 MB  [T][4H]
  float*    hs   = (float*)(ws + (64u << 20));          // 16 MB  [T][H]
  short*    xb   = (short*)(ws + (80u << 20));          // 4 MB
  short*    wb   = (short*)(ws + (84u << 20));          // 16 MB
  unsigned long long* ring = (unsigned long long*)(ws + (100u << 20)); // 8 MB [RING][H]
  float*    dtp  = (float*)(ws + (108u << 20));
  float*    attn = dtp + T;
  unsigned* flags = (unsigned*)(attn + T);

  prep_kernel<<<8192, 256, 0, stream>>>(x, W_ih, time_, xb, wb, dtp, flags);

  gemm_xg<<<2048, 256, 0, stream>>>(xb, wb, b_ih, b_hh, xg);

  {
    void* args[] = {&xg, (void*)&W_hh, (void*)&decay_w, (void*)&decay_b,
                    (void*)&h0, (void*)&c0, &dtp, &hs, &ring, &flags};
    (void)hipLaunchCooperativeKernel((void*)lstm_rec, dim3(NBLK), dim3(512), args, 0, stream);
  }

  attn_k<<<T, 256, 0, stream>>>(hs, attn);
  softmax_k<<<1, 1024, 0, stream>>>(attn);
  (void)hipMemsetAsync(d_out, 0, out_size * sizeof(float), stream);
  ctx_k<<<dim3(H / 256, T / 64), 256, 0, stream>>>(hs, attn, (float*)d_out);
}